// Round 5
// baseline (64.678 us; speedup 1.0000x reference)
//
#include <hip/hip_runtime.h>
#include <math.h>

#define HW     262144   // 512*512
#define WIDTH  512
#define BB     4
#define NN     32
#define KK     256
#define PP     8192
#define EPSF   1e-4f
#define ONE_M_EPS (1.0f - 1e-4f)
#define NEG_LOG_EPS 9.2103403719f    // -ln(1e-4)
#define NEG_LOG_1ME 1.00005003e-4f   // -ln(1-1e-4)

// ---- block partition: inst first (longest), then streaming families ----
#define NBLK_INST  1024  // 16 (b,g) x 64 blocks; 4 waves/block, 4 items/wave
#define NBLK_WH    256
#define NBLK_FOCAL 512   // 2 tensors x 256
#define NBLK_TAN   32
#define NBLK_VAR   128
#define OFF_WH     NBLK_INST
#define OFF_FOCAL  (OFF_WH + NBLK_WH)
#define OFF_TAN    (OFF_FOCAL + NBLK_FOCAL)
#define OFF_VAR    (OFF_TAN + NBLK_TAN)
#define NBLK_TOTAL (OFF_VAR + NBLK_VAR)   // 1952

// ---- workspace layout (floats) ----
#define WS_INST  0       // [16 bg][64 blk][16]  (il*2 + {sum,cnt})  = 16384
#define WS_FOCAL 16384   // [2][256][2] = 1024
#define WS_WH    17408   // [256][2]    = 512
#define WS_TAN   17920   // [32]
#define WS_VAR   17952   // [128]
// total 18080 floats = 72,320 bytes

__device__ __forceinline__ float ftanh(float x) {
    float e = __expf(2.0f * x);
    return 1.0f - 2.0f / (e + 1.0f);
}

__device__ __forceinline__ float wave_reduce(float v) {
    #pragma unroll
    for (int off = 1; off < 64; off <<= 1) v += __shfl_xor(v, off, 64);
    return v;
}

__device__ __forceinline__ float block_reduce(float v, float* sbuf) {
    v = wave_reduce(v);
    int lane = threadIdx.x & 63, wid = threadIdx.x >> 6;
    __syncthreads();
    if (lane == 0) sbuf[wid] = v;
    __syncthreads();
    float r = 0.f;
    if (threadIdx.x == 0) {
        for (int i = 0; i < 4; ++i) r += sbuf[i];
    }
    return r;
}

// async global->LDS, 16 B per lane: LDS dest = wave-uniform base + lane*16,
// global src = per-lane address. Tracked by vmcnt.
__device__ __forceinline__ void glds16(const void* g, void* l) {
    __builtin_amdgcn_global_load_lds(
        (const __attribute__((address_space(1))) void*)g,
        (__attribute__((address_space(3))) void*)l, 16, 0, 0);
}

// ---- AE instance focal: LDS-staged deep prefetch pipeline ----
// idx in [0,1024): bg = idx>>6 (b=bg>>2, g=bg&3), blk = idx&63.
// Each of 4 waves: 4 items; item = 64 float4 (256 px) x 8 instances.
// Steady state: 12 x 1KB gl_lds in flight per wave; waits are vmcnt(8).
__device__ __forceinline__ void inst_part(int idx, const float* __restrict__ ae,
                                          const float* __restrict__ masks,
                                          const int* __restrict__ centers,
                                          float* __restrict__ ws,
                                          float4* s_mask,   // [4][2*4*64]
                                          float4* s_ae,     // [4][4*64]
                                          float* s_red) {   // [4][16]
    const int tid = threadIdx.x, w = tid >> 6, lane = tid & 63;
    const int bg = idx >> 6, blk = idx & 63;
    const int b = bg >> 2, g = bg & 3;
    float4* mbuf = s_mask + w * (2 * 4 * 64);   // wave-local [2][4][64]
    float4* abuf = s_ae + w * (4 * 64);         // wave-local [4][64]

    // centers -> wave-uniform scalars (readfirstlane => SGPRs)
    float cyv[8], cxv[8];
    #pragma unroll
    for (int il = 0; il < 8; ++il) {
        int cb = (b * NN + g * 8 + il) * 2;
        cyv[il] = (float)__builtin_amdgcn_readfirstlane(centers[cb]) * (1.0f / 512.0f);
        cxv[il] = (float)__builtin_amdgcn_readfirstlane(centers[cb + 1]) * (1.0f / 512.0f);
    }
    asm volatile("s_waitcnt vmcnt(0)" ::: "memory");   // drain center loads

    const int c0 = blk * 16 + w * 4;   // first of 4 chunks (64 float4 each)
    const float4* mbase = (const float4*)masks + (size_t)(b * NN + g * 8) * 65536;
    const float4* abase = (const float4*)ae + (size_t)b * 4 * 65536;

#define ISSUE_AE(item) do { int v_ = (c0 + (item)) * 64 + lane;          \
        glds16(abase + 0 * 65536 + v_, abuf + 0 * 64);                   \
        glds16(abase + 1 * 65536 + v_, abuf + 1 * 64);                   \
        glds16(abase + 2 * 65536 + v_, abuf + 2 * 64);                   \
        glds16(abase + 3 * 65536 + v_, abuf + 3 * 64); } while (0)
#define ISSUE_MH(item, hb) do { int v_ = (c0 + (item)) * 64 + lane;      \
        glds16(mbase + ((hb) * 4 + 0) * 65536 + v_, mbuf + ((hb) * 4 + 0) * 64); \
        glds16(mbase + ((hb) * 4 + 1) * 65536 + v_, mbuf + ((hb) * 4 + 1) * 64); \
        glds16(mbase + ((hb) * 4 + 2) * 65536 + v_, mbuf + ((hb) * 4 + 2) * 64); \
        glds16(mbase + ((hb) * 4 + 3) * 65536 + v_, mbuf + ((hb) * 4 + 3) * 64); } while (0)

    float a_sum[8], a_cnt[8];
    #pragma unroll
    for (int i = 0; i < 8; ++i) { a_sum[i] = 0.f; a_cnt[i] = 0.f; }

    // prologue: 12 loads in flight {ae0, mhA0, mhB0}
    ISSUE_AE(0);
    ISSUE_MH(0, 0);
    ISSUE_MH(0, 1);

    #pragma unroll
    for (int i = 0; i < 4; ++i) {
        // ae_i landed (drain oldest 4 of 12)
        asm volatile("s_waitcnt vmcnt(8)" ::: "memory");
        float4 a0 = abuf[0 * 64 + lane];
        float4 a1 = abuf[1 * 64 + lane];
        float4 a2 = abuf[2 * 64 + lane];
        float4 a3 = abuf[3 * 64 + lane];
        int v = (c0 + i) * 64 + lane;
        int pix0 = v * 4;
        float fy  = (float)(pix0 >> 9)  * (1.0f / 512.0f);
        float fx0 = (float)(pix0 & 511) * (1.0f / 512.0f);
        float se0[4], se1[4], sg0[4], sg1[4];
        #pragma unroll
        for (int j = 0; j < 4; ++j) {
            se0[j] = ftanh((&a0.x)[j]) + fy;
            se1[j] = ftanh((&a1.x)[j]) + fx0 + (float)j * (1.0f / 512.0f);
            sg0[j] = __expf((&a2.x)[j]);
            sg1[j] = __expf((&a3.x)[j]);
        }
        asm volatile("s_waitcnt lgkmcnt(0)" ::: "memory");  // abuf reads done
        if (i < 3) ISSUE_AE(i + 1);                          // overwrite abuf

        // ---- half 0 (instances il = 0..3) ----
        if (i < 3) { asm volatile("s_waitcnt vmcnt(8)" ::: "memory"); }
        else       { asm volatile("s_waitcnt vmcnt(4)" ::: "memory"); }
        #pragma unroll
        for (int k = 0; k < 4; ++k) {
            float4 mk = mbuf[k * 64 + lane];
            #pragma unroll
            for (int j = 0; j < 4; ++j) {
                float m  = (&mk.x)[j];                 // exactly 0.0 or 1.0
                float dy = se0[j] - cyv[k], dx = se1[j] - cxv[k];
                float s  = fmaf(dx * dx, sg1[j], dy * dy * sg0[j]);
                float e  = __expf(-s);
                float pc = fminf(fmaxf(e, EPSF), ONE_M_EPS);
                float omp = 1.0f - pc;
                float lp  = -fminf(fmaxf(s, NEG_LOG_1ME), NEG_LOG_EPS);
                float pos_t = lp * omp * omp;
                float neg_t = __logf(omp) * pc * pc;   // neg_w == 1 (binary masks)
                a_sum[k] += (m != 0.f) ? pos_t : neg_t;
                a_cnt[k] += m;
            }
        }
        asm volatile("s_waitcnt lgkmcnt(0)" ::: "memory");  // mbuf[0] reads done
        if (i < 3) ISSUE_MH(i + 1, 0);

        // ---- half 1 (instances il = 4..7) ----
        if (i < 3) { asm volatile("s_waitcnt vmcnt(8)" ::: "memory"); }
        else       { asm volatile("s_waitcnt vmcnt(0)" ::: "memory"); }
        #pragma unroll
        for (int k = 0; k < 4; ++k) {
            float4 mk = mbuf[(4 + k) * 64 + lane];
            #pragma unroll
            for (int j = 0; j < 4; ++j) {
                float m  = (&mk.x)[j];
                float dy = se0[j] - cyv[4 + k], dx = se1[j] - cxv[4 + k];
                float s  = fmaf(dx * dx, sg1[j], dy * dy * sg0[j]);
                float e  = __expf(-s);
                float pc = fminf(fmaxf(e, EPSF), ONE_M_EPS);
                float omp = 1.0f - pc;
                float lp  = -fminf(fmaxf(s, NEG_LOG_1ME), NEG_LOG_EPS);
                float pos_t = lp * omp * omp;
                float neg_t = __logf(omp) * pc * pc;
                a_sum[4 + k] += (m != 0.f) ? pos_t : neg_t;
                a_cnt[4 + k] += m;
            }
        }
        asm volatile("s_waitcnt lgkmcnt(0)" ::: "memory");
        if (i < 3) ISSUE_MH(i + 1, 1);
    }
#undef ISSUE_AE
#undef ISSUE_MH

    // block reduction: wave-reduce 16 values, sum across 4 waves
    #pragma unroll
    for (int il = 0; il < 8; ++il) {
        float v0 = wave_reduce(a_sum[il]);
        float v1 = wave_reduce(a_cnt[il]);
        if (lane == 0) { s_red[w * 16 + il * 2] = v0; s_red[w * 16 + il * 2 + 1] = v1; }
    }
    __syncthreads();
    if (tid < 16) {
        float s = s_red[tid] + s_red[16 + tid] + s_red[32 + tid] + s_red[48 + tid];
        ws[WS_INST + (bg * 64 + blk) * 16 + tid] = s;
    }
}

// ---- cls/kp focal: idx = t*256 + blk, 4 iters ----
__device__ __forceinline__ void focal_part(int idx, const float* __restrict__ cls_out,
                                           const float* __restrict__ cls_mask,
                                           const float* __restrict__ kp_out,
                                           const float* __restrict__ kp_mask,
                                           float* __restrict__ ws, float* sbuf) {
    int t = idx >> 8, blk = idx & 255;
    const float4* po = (const float4*)(t == 0 ? cls_out : kp_out);
    const float4* pm = (const float4*)(t == 0 ? cls_mask : kp_mask);
    float sum = 0.f, cnt = 0.f;
    #pragma unroll
    for (int it = 0; it < 4; ++it) {
        int i = blk * 256 + threadIdx.x + it * 65536;
        float4 xo = po[i], xm = pm[i];
        #pragma unroll
        for (int j = 0; j < 4; ++j) {
            float x = (&xo.x)[j], gt = (&xm.x)[j];
            float p = 1.0f / (1.0f + __expf(-x));
            p = fminf(fmaxf(p, EPSF), ONE_M_EPS);
            float omp = 1.0f - p;
            float pos_t = __logf(p) * omp * omp;
            float og = 1.0f - gt;
            float negw = og * og; negw *= negw;
            float neg_t = __logf(omp) * p * p * negw;
            bool ispos = (gt == 1.0f);
            sum += ispos ? pos_t : neg_t;
            cnt += ispos ? 1.0f : 0.0f;
        }
    }
    float r0 = block_reduce(sum, sbuf);
    float r1 = block_reduce(cnt, sbuf);
    if (threadIdx.x == 0) {
        ws[WS_FOCAL + idx * 2 + 0] = r0;
        ws[WS_FOCAL + idx * 2 + 1] = r1;
    }
}

__device__ __forceinline__ void wh_part(int blk, const float* __restrict__ o,
                                        const float* __restrict__ tg,
                                        const float* __restrict__ m,
                                        float* __restrict__ ws, float* sbuf) {
    const float4* po  = (const float4*)o;
    const float4* pt  = (const float4*)tg;
    const float4* pmk = (const float4*)m;
    float sl = 0.f, ms = 0.f;
    #pragma unroll
    for (int it = 0; it < 8; ++it) {
        int i = blk * 256 + threadIdx.x + it * 65536;
        float4 a = po[i], b = pt[i], c = pmk[i];
        #pragma unroll
        for (int j = 0; j < 4; ++j) {
            float mm = (&c.x)[j];
            float d  = (&a.x)[j] * mm - (&b.x)[j] * mm;
            float ad = fabsf(d);
            sl += (ad < 1.0f) ? 0.5f * d * d : (ad - 0.5f);
            ms += mm;
        }
    }
    float r0 = block_reduce(sl, sbuf);
    float r1 = block_reduce(ms, sbuf);
    if (threadIdx.x == 0) {
        ws[WS_WH + blk * 2 + 0] = r0;
        ws[WS_WH + blk * 2 + 1] = r1;
    }
}

__device__ __forceinline__ void tan_part(int idx, const float* __restrict__ tan_out,
                                         const float* __restrict__ normals,
                                         const int* __restrict__ pts,
                                         float* __restrict__ ws, float* sbuf) {
    int b = idx >> 3, seg = idx & 7;
    float s = 0.f;
    for (int p = seg * 1024 + threadIdx.x; p < seg * 1024 + 1024; p += 256) {
        int base = (b * PP + p) * 2;
        int py = pts[base], px = pts[base + 1];
        int pix = py * WIDTH + px;
        float t0 = tan_out[b * 2 * HW + pix];
        float t1 = tan_out[b * 2 * HW + HW + pix];
        float inv = 1.0f / fmaxf(sqrtf(t0 * t0 + t1 * t1), EPSF);
        float n0 = normals[base], n1 = normals[base + 1];
        s += 1.0f - (n0 * t0 + n1 * t1) * inv;
    }
    float r = block_reduce(s, sbuf);
    if (threadIdx.x == 0) ws[WS_TAN + idx] = r;
}

__device__ __forceinline__ void var_part(int idx, const float* __restrict__ ae,
                                         const int* __restrict__ centers,
                                         const int* __restrict__ kps,
                                         float* __restrict__ ws, float* smem) {
    int n = idx & 31, b = idx >> 5;
    float* cy = smem, *cx = smem + 32, *sbuf = smem + 64;
    if (threadIdx.x < NN) {
        int cb = (b * NN + threadIdx.x) * 2;
        cy[threadIdx.x] = centers[cb]     * (1.0f / 512.0f);
        cx[threadIdx.x] = centers[cb + 1] * (1.0f / 512.0f);
    }
    __syncthreads();
    int k = threadIdx.x;
    int kb = ((b * NN + n) * KK + k) * 2;
    int ky = kps[kb], kx = kps[kb + 1];
    int pix = ky * WIDTH + kx;
    const float* aeb = ae + (size_t)b * 4 * HW;
    float se0 = ftanh(aeb[pix])      + ky * (1.0f / 512.0f);
    float se1 = ftanh(aeb[HW + pix]) + kx * (1.0f / 512.0f);
    float sg0 = __expf(aeb[2 * HW + pix]);
    float sg1 = __expf(aeb[3 * HW + pix]);
    float own = 0.f, mx = -1e30f;
    #pragma unroll
    for (int m = 0; m < NN; ++m) {
        float d0 = se0 - cy[m], d1 = se1 - cx[m];
        float dist = __expf(-(d0 * d0 * sg0 + d1 * d1 * sg1));
        mx = fmaxf(mx, dist);
        if (m == n) own = dist;
    }
    float r = block_reduce(fabsf(own - mx), sbuf);
    if (threadIdx.x == 0) ws[WS_VAR + b * NN + n] = r;
}

// ---- the mega kernel ----
__global__ void __launch_bounds__(256, 2)
k_mega(const float* __restrict__ cls_out, const float* __restrict__ wh_out,
       const float* __restrict__ kp_out,  const float* __restrict__ ae_out,
       const float* __restrict__ tan_out, const float* __restrict__ cls_mask,
       const float* __restrict__ wh_target, const float* __restrict__ wh_mask,
       const float* __restrict__ kp_mask, const float* __restrict__ ae_masks,
       const float* __restrict__ tan_normals,
       const int* __restrict__ centers, const int* __restrict__ kps,
       const int* __restrict__ tan_points, float* __restrict__ ws) {
    __shared__ float4 s_mask[4 * 2 * 4 * 64];   // 32 KB, per-wave double-buffered masks
    __shared__ float4 s_ae[4 * 4 * 64];         // 16 KB, per-wave ae staging
    __shared__ float  s_red[4 * 16];
    __shared__ float  s_misc[160];
    int bid = blockIdx.x;
    if (bid < NBLK_INST) {
        inst_part(bid, ae_out, ae_masks, centers, ws, s_mask, s_ae, s_red);
    } else if (bid < OFF_FOCAL) {
        wh_part(bid - OFF_WH, wh_out, wh_target, wh_mask, ws, s_misc);
    } else if (bid < OFF_TAN) {
        focal_part(bid - OFF_FOCAL, cls_out, cls_mask, kp_out, kp_mask, ws, s_misc);
    } else if (bid < OFF_VAR) {
        tan_part(bid - OFF_TAN, tan_out, tan_normals, tan_points, ws, s_misc);
    } else {
        var_part(bid - OFF_VAR, ae_out, centers, kps, ws, s_misc);
    }
}

// ---- finalize: 1 block ----
__global__ void __launch_bounds__(256)
k_final(const float* __restrict__ ws, float* __restrict__ out) {
    __shared__ float sbuf[4];
    int tid = threadIdx.x;
    float ae_v = 0.f;
    if (tid < 128) {   // tid = b*32 + n
        int b = tid >> 5, n = tid & 31, g = n >> 3, il = n & 7;
        const float* base = ws + WS_INST + (b * 4 + g) * 64 * 16 + il * 2;
        float sum = 0.f, cnt = 0.f;
        #pragma unroll 8
        for (int k = 0; k < 64; ++k) { sum += base[k * 16]; cnt += base[k * 16 + 1]; }
        // where(np>0, -(pos+neg)/max(np,1), -neg) == -sum/max(np,1)  (np==0 => pos==0)
        ae_v = -sum / fmaxf(cnt, 1.0f) + ws[WS_VAR + tid];
    }
    float ae_sum = block_reduce(ae_v, sbuf);

    float cls_sum = block_reduce(ws[WS_FOCAL + tid * 2], sbuf);
    float cls_cnt = block_reduce(ws[WS_FOCAL + tid * 2 + 1], sbuf);
    float kp_sum  = block_reduce(ws[WS_FOCAL + 512 + tid * 2], sbuf);
    float kp_cnt  = block_reduce(ws[WS_FOCAL + 512 + tid * 2 + 1], sbuf);
    float wh_sl   = block_reduce(ws[WS_WH + tid * 2], sbuf);
    float wh_ms   = block_reduce(ws[WS_WH + tid * 2 + 1], sbuf);
    float tan_sum = block_reduce(tid < 32 ? ws[WS_TAN + tid] : 0.f, sbuf);

    if (tid == 0) {
        float l_cls = -cls_sum / fmaxf(cls_cnt, 1.0f);
        float l_kp  = -kp_sum  / fmaxf(kp_cnt,  1.0f);
        float l_wh  = 0.1f * wh_sl / (wh_ms + 1e-4f);
        float l_ae  = ae_sum / (float)(NN * BB);
        float l_tan = tan_sum / (float)(PP * BB);
        out[0] = l_cls + l_wh + l_kp + l_ae + l_tan;
    }
}

extern "C" void kernel_launch(void* const* d_in, const int* in_sizes, int n_in,
                              void* d_out, int out_size, void* d_ws, size_t ws_size,
                              hipStream_t stream) {
    const float* cls_out     = (const float*)d_in[0];
    const float* wh_out      = (const float*)d_in[1];
    const float* kp_out      = (const float*)d_in[2];
    const float* ae_out      = (const float*)d_in[3];
    const float* tan_out     = (const float*)d_in[4];
    const float* cls_mask    = (const float*)d_in[5];
    const float* wh_target   = (const float*)d_in[6];
    const float* wh_mask     = (const float*)d_in[7];
    const float* kp_mask     = (const float*)d_in[8];
    const float* ae_masks    = (const float*)d_in[9];
    const float* tan_normals = (const float*)d_in[10];
    // d_in[11] = xym: analytic (y/512, x/512)
    const int* centers    = (const int*)d_in[12];
    const int* kps        = (const int*)d_in[13];
    const int* tan_points = (const int*)d_in[14];
    float* ws  = (float*)d_ws;
    float* out = (float*)d_out;

    k_mega<<<NBLK_TOTAL, 256, 0, stream>>>(cls_out, wh_out, kp_out, ae_out, tan_out,
                                           cls_mask, wh_target, wh_mask, kp_mask,
                                           ae_masks, tan_normals, centers, kps,
                                           tan_points, ws);
    k_final<<<1, 256, 0, stream>>>(ws, out);
}